// Round 1
// baseline (280.448 us; speedup 1.0000x reference)
//
#include <hip/hip_runtime.h>

// InnerSelfAttention (sliding-window causal, WIN=256, unscaled QK^T) for MI355X.
// Pipeline: split fp32->bf16(hi,lo) -> bf16x3 Q/K proj -> bf16 V proj (transposed)
//           -> flash attention (bf16x3 QK^T, fp32 softmax, bf16 PV)
//           -> bf16 O proj + bias (fp32 out).
// B=2 S=2048 E=1024 H=16 D=64 WIN=256.

typedef __bf16 bf16x8 __attribute__((ext_vector_type(8)));
typedef short s16x8 __attribute__((ext_vector_type(8)));
typedef float f32x4 __attribute__((ext_vector_type(4)));
typedef unsigned short u16;

#define DEV __device__ __forceinline__

DEV u16 f2bf(float f) {  // RNE float->bf16
  unsigned u = __builtin_bit_cast(unsigned, f);
  u += 0x7FFFu + ((u >> 16) & 1u);
  return (u16)(u >> 16);
}
DEV float bf2f(u16 h) {
  unsigned u = ((unsigned)h) << 16;
  return __builtin_bit_cast(float, u);
}

#define MFMA16(a, b, c) __builtin_amdgcn_mfma_f32_16x16x32_bf16((a), (b), (c), 0, 0, 0)

// ---------------- convert / split kernels ----------------
template <bool LO>
__global__ __launch_bounds__(256) void cvt_split(const float* __restrict__ src,
                                                 u16* __restrict__ hi,
                                                 u16* __restrict__ lo, int n4) {
  for (int i = blockIdx.x * 256 + threadIdx.x; i < n4; i += gridDim.x * 256) {
    f32x4 v = ((const f32x4*)src)[i];
    unsigned long long ph = 0, pl = 0;
#pragma unroll
    for (int c = 0; c < 4; ++c) {
      u16 h = f2bf(v[c]);
      ph |= ((unsigned long long)h) << (16 * c);
      if (LO) {
        u16 l = f2bf(v[c] - bf2f(h));
        pl |= ((unsigned long long)l) << (16 * c);
      }
    }
    ((unsigned long long*)hi)[i] = ph;
    if (LO) ((unsigned long long*)lo)[i] = pl;
  }
}

// ---------------- NT GEMM: C[M=4096][N=1024] = A[M][1024] . Bt[N][1024]^T ----
// MODE 0: bf16x3 (A=xh/xl, B=Wh/Wl), epilogue split->q/k hi,lo in [B,H,S,D]
// MODE 1: bf16,   epilogue bf16 -> vT [B,H,D,S]
// MODE 2: bf16,   epilogue fp32 + bias -> out [M][N]
template <int MODE>
__global__ __launch_bounds__(256) void gemm_kernel(
    const u16* __restrict__ Ah, const u16* __restrict__ Al,
    const u16* __restrict__ Bh, const u16* __restrict__ Bl,
    u16* __restrict__ O1, u16* __restrict__ O2,
    const float* __restrict__ bias, float* __restrict__ Of) {
  constexpr bool SPLIT = (MODE == 0);
  constexpr int NS = SPLIT ? 2 : 1;
  constexpr int BKP = 40;  // 32 + 8 pad: 80B row stride -> 2-way bank alias (free)
  __shared__ u16 sA[NS][128][BKP];
  __shared__ u16 sB[NS][128][BKP];

  const int tid = threadIdx.x;
  const int lane = tid & 63, w = tid >> 6;
  const int lr = lane & 15, lg = lane >> 4;
  const int wr = w >> 1, wc = w & 1;
  const int m0 = blockIdx.y * 128, n0 = blockIdx.x * 128;

  f32x4 acc[4][4];
#pragma unroll
  for (int i = 0; i < 4; ++i)
#pragma unroll
    for (int j = 0; j < 4; ++j)
#pragma unroll
      for (int e = 0; e < 4; ++e) acc[i][j][e] = 0.f;

  for (int k0 = 0; k0 < 1024; k0 += 32) {
// stage 128x32 bf16 tiles (reg-staged; padded LDS)
#pragma unroll
    for (int c = 0; c < 2; ++c) {
      int cid = c * 256 + tid;
      int row = cid >> 2, col8 = (cid & 3) * 8;
      size_t aoff = (size_t)(m0 + row) * 1024 + k0 + col8;
      size_t boff = (size_t)(n0 + row) * 1024 + k0 + col8;
      *(s16x8*)&sA[0][row][col8] = *(const s16x8*)&Ah[aoff];
      *(s16x8*)&sB[0][row][col8] = *(const s16x8*)&Bh[boff];
      if constexpr (SPLIT) {
        *(s16x8*)&sA[1][row][col8] = *(const s16x8*)&Al[aoff];
        *(s16x8*)&sB[1][row][col8] = *(const s16x8*)&Bl[boff];
      }
    }
    __syncthreads();

    bf16x8 fah[4], fbh[4], fal[4], fbl[4];
#pragma unroll
    for (int f = 0; f < 4; ++f) {
      fah[f] = *(const bf16x8*)&sA[0][wr * 64 + f * 16 + lr][lg * 8];
      fbh[f] = *(const bf16x8*)&sB[0][wc * 64 + f * 16 + lr][lg * 8];
      if constexpr (SPLIT) {
        fal[f] = *(const bf16x8*)&sA[1][wr * 64 + f * 16 + lr][lg * 8];
        fbl[f] = *(const bf16x8*)&sB[1][wc * 64 + f * 16 + lr][lg * 8];
      }
    }
#pragma unroll
    for (int i = 0; i < 4; ++i)
#pragma unroll
      for (int j = 0; j < 4; ++j) {
        acc[i][j] = MFMA16(fah[i], fbh[j], acc[i][j]);
        if constexpr (SPLIT) {
          acc[i][j] = MFMA16(fah[i], fbl[j], acc[i][j]);
          acc[i][j] = MFMA16(fal[i], fbh[j], acc[i][j]);
        }
      }
    __syncthreads();
  }

// epilogue. C layout (verified m89): col = lane&15, row = (lane>>4)*4 + e
#pragma unroll
  for (int i = 0; i < 4; ++i)
#pragma unroll
    for (int j = 0; j < 4; ++j)
#pragma unroll
      for (int e = 0; e < 4; ++e) {
        float v = acc[i][j][e];
        int mm = m0 + wr * 64 + i * 16 + lg * 4 + e;
        int nn = n0 + wc * 64 + j * 16 + lr;
        if constexpr (MODE == 0) {
          int bb = mm >> 11, ss = mm & 2047, hh = nn >> 6, dd = nn & 63;
          size_t idx = ((size_t)(bb * 16 + hh) * 2048 + ss) * 64 + dd;
          u16 h = f2bf(v);
          O1[idx] = h;
          O2[idx] = f2bf(v - bf2f(h));
        } else if constexpr (MODE == 1) {
          int bb = mm >> 11, ss = mm & 2047, hh = nn >> 6, dd = nn & 63;
          size_t idx = ((size_t)(bb * 16 + hh) * 64 + dd) * 2048 + ss;
          O1[idx] = f2bf(v);
        } else {
          Of[(size_t)mm * 1024 + nn] = v + bias[nn];
        }
      }
}

// ---------------- flash attention, 64-query blocks, 64-key tiles ------------
__global__ __launch_bounds__(256) void attn_kernel(
    const u16* __restrict__ qh, const u16* __restrict__ ql,
    const u16* __restrict__ kh, const u16* __restrict__ kl,
    const u16* __restrict__ vT, u16* __restrict__ ctx) {
  const int qt = blockIdx.x, hd = blockIdx.y, b = blockIdx.z;
  const int q0 = qt * 64;
  const int bh = b * 16 + hd;
  const int tid = threadIdx.x;
  const int lane = tid & 63, w = tid >> 6;
  const int lr = lane & 15, lg = lane >> 4;

  __shared__ u16 sKh[64][72];  // [key][d], 144B rows -> 2-way alias
  __shared__ u16 sKl[64][72];
  __shared__ u16 sVT[64][72];  // [d][key]
  __shared__ u16 sP[4][16][72];  // per-wave P tile [q][key]

  // hoisted Q fragments: wave w owns queries q0+16w .. +15
  bf16x8 qfh[2], qfl[2];
  const size_t qbase = ((size_t)bh * 2048 + q0 + w * 16 + lr) * 64;
#pragma unroll
  for (int ks = 0; ks < 2; ++ks) {
    qfh[ks] = *(const bf16x8*)&qh[qbase + ks * 32 + lg * 8];
    qfl[ks] = *(const bf16x8*)&ql[qbase + ks * 32 + lg * 8];
  }

  float mrow[4], lrow[4];
  f32x4 cf[4];
#pragma unroll
  for (int e = 0; e < 4; ++e) { mrow[e] = -__builtin_inff(); lrow[e] = 0.f; }
#pragma unroll
  for (int nd = 0; nd < 4; ++nd)
#pragma unroll
    for (int e = 0; e < 4; ++e) cf[nd][e] = 0.f;

  const int t0 = (qt >= 4) ? qt - 4 : 0;
  for (int t = t0; t <= qt; ++t) {
    const int k0 = t * 64;
// stage K(hi,lo) and V^T tiles
#pragma unroll
    for (int c = 0; c < 2; ++c) {
      int cid = c * 256 + tid;
      int row = cid >> 3, col8 = (cid & 7) * 8;
      size_t kidx = ((size_t)bh * 2048 + k0 + row) * 64 + col8;
      size_t vidx = ((size_t)bh * 64 + row) * 2048 + k0 + col8;
      *(s16x8*)&sKh[row][col8] = *(const s16x8*)&kh[kidx];
      *(s16x8*)&sKl[row][col8] = *(const s16x8*)&kl[kidx];
      *(s16x8*)&sVT[row][col8] = *(const s16x8*)&vT[vidx];
    }
    __syncthreads();

    // scores: 16q x 64k, bf16x3 over D=64
    f32x4 sc[4];
#pragma unroll
    for (int nf = 0; nf < 4; ++nf)
#pragma unroll
      for (int e = 0; e < 4; ++e) sc[nf][e] = 0.f;
#pragma unroll
    for (int ks = 0; ks < 2; ++ks)
#pragma unroll
      for (int nf = 0; nf < 4; ++nf) {
        bf16x8 kbh = *(const bf16x8*)&sKh[nf * 16 + lr][ks * 32 + lg * 8];
        bf16x8 kbl = *(const bf16x8*)&sKl[nf * 16 + lr][ks * 32 + lg * 8];
        sc[nf] = MFMA16(qfh[ks], kbh, sc[nf]);
        sc[nf] = MFMA16(qfh[ks], kbl, sc[nf]);
        sc[nf] = MFMA16(qfl[ks], kbh, sc[nf]);
      }

    // band mask: allowed iff key <= q && key+256 > q (only boundary tiles)
    const bool masked = (k0 < q0 - 192) || (k0 >= q0);
    if (masked) {
#pragma unroll
      for (int nf = 0; nf < 4; ++nf) {
        int key = k0 + nf * 16 + lr;
#pragma unroll
        for (int e = 0; e < 4; ++e) {
          int qi = q0 + w * 16 + lg * 4 + e;
          if (key > qi || key + 256 <= qi) sc[nf][e] = -__builtin_inff();
        }
      }
    }

    // online softmax (rows spread across lanes lr=0..15 within lg group)
    float rm[4];
#pragma unroll
    for (int e = 0; e < 4; ++e)
      rm[e] = fmaxf(fmaxf(sc[0][e], sc[1][e]), fmaxf(sc[2][e], sc[3][e]));
#pragma unroll
    for (int off = 1; off < 16; off <<= 1)
#pragma unroll
      for (int e = 0; e < 4; ++e) rm[e] = fmaxf(rm[e], __shfl_xor(rm[e], off));

    float alpha[4], mu[4];
#pragma unroll
    for (int e = 0; e < 4; ++e) {
      float mn = fmaxf(mrow[e], rm[e]);
      bool ninf = (mn == -__builtin_inff());  // fully-masked row in this tile
      mu[e] = ninf ? 0.f : mn;
      alpha[e] = ninf ? 1.f : __expf(mrow[e] - mn);
      mrow[e] = mn;
    }
    float p[4][4], rs[4];
#pragma unroll
    for (int nf = 0; nf < 4; ++nf)
#pragma unroll
      for (int e = 0; e < 4; ++e) p[nf][e] = __expf(sc[nf][e] - mu[e]);
#pragma unroll
    for (int e = 0; e < 4; ++e) rs[e] = p[0][e] + p[1][e] + p[2][e] + p[3][e];
#pragma unroll
    for (int off = 1; off < 16; off <<= 1)
#pragma unroll
      for (int e = 0; e < 4; ++e) rs[e] += __shfl_xor(rs[e], off);
#pragma unroll
    for (int e = 0; e < 4; ++e) lrow[e] = lrow[e] * alpha[e] + rs[e];
#pragma unroll
    for (int nd = 0; nd < 4; ++nd)
#pragma unroll
      for (int e = 0; e < 4; ++e) cf[nd][e] *= alpha[e];

// P -> per-wave LDS (relayout to A-fragment), then PV
#pragma unroll
    for (int nf = 0; nf < 4; ++nf)
#pragma unroll
      for (int e = 0; e < 4; ++e)
        sP[w][lg * 4 + e][nf * 16 + lr] = f2bf(p[nf][e]);

#pragma unroll
    for (int ks = 0; ks < 2; ++ks) {
      bf16x8 pa = *(const bf16x8*)&sP[w][lr][ks * 32 + lg * 8];
#pragma unroll
      for (int nd = 0; nd < 4; ++nd) {
        bf16x8 vb = *(const bf16x8*)&sVT[nd * 16 + lr][ks * 32 + lg * 8];
        cf[nd] = MFMA16(pa, vb, cf[nd]);
      }
    }
    __syncthreads();
  }

// epilogue: ctx[b,s,h*64+d] bf16
#pragma unroll
  for (int nd = 0; nd < 4; ++nd)
#pragma unroll
    for (int e = 0; e < 4; ++e) {
      float v = cf[nd][e] / lrow[e];
      size_t o = ((size_t)(b * 2048 + q0 + w * 16 + lg * 4 + e)) * 1024 +
                 hd * 64 + nd * 16 + lr;
      ctx[o] = f2bf(v);
    }
}

// ---------------- launch ----------------
extern "C" void kernel_launch(void* const* d_in, const int* in_sizes, int n_in,
                              void* d_out, int out_size, void* d_ws, size_t ws_size,
                              hipStream_t stream) {
  (void)in_sizes; (void)n_in; (void)out_size; (void)ws_size;
  const float* x  = (const float*)d_in[0];
  const float* Wq = (const float*)d_in[1];
  const float* Wk = (const float*)d_in[2];
  const float* Wv = (const float*)d_in[3];
  const float* Wo = (const float*)d_in[4];
  const float* bo = (const float*)d_in[5];
  float* out = (float*)d_out;
  char* ws = (char*)d_ws;

  constexpr size_t TEN = 8388608;   // 4.19M u16
  constexpr size_t WTEN = 2097152;  // 1.05M u16
  u16* xh  = (u16*)(ws + 0 * TEN);
  u16* xl  = (u16*)(ws + 1 * TEN);
  u16* qh  = (u16*)(ws + 2 * TEN);
  u16* ql  = (u16*)(ws + 3 * TEN);
  u16* kh  = (u16*)(ws + 4 * TEN);
  u16* kl  = (u16*)(ws + 5 * TEN);
  u16* vT  = (u16*)(ws + 6 * TEN);
  u16* ctx = (u16*)(ws + 7 * TEN);
  char* wb = ws + 8 * TEN;
  u16* wqh = (u16*)(wb + 0 * WTEN);
  u16* wql = (u16*)(wb + 1 * WTEN);
  u16* wkh = (u16*)(wb + 2 * WTEN);
  u16* wkl = (u16*)(wb + 3 * WTEN);
  u16* wvh = (u16*)(wb + 4 * WTEN);
  u16* woh = (u16*)(wb + 5 * WTEN);

  cvt_split<true><<<1024, 256, 0, stream>>>(x, xh, xl, 4194304 / 4);
  cvt_split<true><<<256, 256, 0, stream>>>(Wq, wqh, wql, 1048576 / 4);
  cvt_split<true><<<256, 256, 0, stream>>>(Wk, wkh, wkl, 1048576 / 4);
  cvt_split<false><<<256, 256, 0, stream>>>(Wv, wvh, nullptr, 1048576 / 4);
  cvt_split<false><<<256, 256, 0, stream>>>(Wo, woh, nullptr, 1048576 / 4);

  dim3 gg(8, 32), bb(256);
  gemm_kernel<0><<<gg, bb, 0, stream>>>(xh, xl, wqh, wql, qh, ql, nullptr, nullptr);
  gemm_kernel<0><<<gg, bb, 0, stream>>>(xh, xl, wkh, wkl, kh, kl, nullptr, nullptr);
  gemm_kernel<1><<<gg, bb, 0, stream>>>(xh, nullptr, wvh, nullptr, vT, nullptr, nullptr, nullptr);
  attn_kernel<<<dim3(32, 16, 2), bb, 0, stream>>>(qh, ql, kh, kl, vT, ctx);
  gemm_kernel<2><<<gg, bb, 0, stream>>>(ctx, nullptr, woh, nullptr, nullptr, nullptr, bo, out);
}